// Round 7
// baseline (134.245 us; speedup 1.0000x reference)
//
#include <hip/hip_runtime.h>
#include <hip/hip_bf16.h>
#include <cmath>

#define B_   4
#define NT_  2048
#define G_   4096
#define DZ_  128

typedef __attribute__((ext_vector_type(8))) short bf16x8;
typedef __attribute__((ext_vector_type(4))) float f32x4;

__device__ __forceinline__ float softplus_f(float x) {
    return fmaxf(x, 0.0f) + log1pf(expf(-fabsf(x)));
}

// z_grid (B,G,DZ) fp32 -> Zt2 tiled bf16: Zt2[((b*128 + c)*128 + z)*32 + gi],
// c = g>>5, gi = g&31.  B-fragments become contiguous 1 KB bursts.
__global__ __launch_bounds__(256, 1)
void transpose_z(const float* __restrict__ z, unsigned short* __restrict__ zt)
{
    __shared__ unsigned short tile[64][66];
    const int bx = blockIdx.x;                // 4b * 64gt * 2zt = 512
    const int zti = bx & 1;
    const int gt  = (bx >> 1) & 63;
    const int b   = bx >> 7;
    const int g0 = gt * 64, z0 = zti * 64;
    const int tid = threadIdx.x;
    const int zl = tid & 63, gl = tid >> 6;
    #pragma unroll
    for (int i = 0; i < 16; ++i) {
        const int g = gl + i * 4;
        const float v = z[(size_t)(b * G_ + g0 + g) * DZ_ + z0 + zl];
        unsigned int u = __float_as_uint(v);
        u = u + 0x7FFFu + ((u >> 16) & 1u);   // RNE to bf16
        tile[g][zl] = (unsigned short)(u >> 16);
    }
    __syncthreads();
    const int gp = (tid & 31) * 2, zi = tid >> 5;
    const int c  = (g0 + gp) >> 5, gi = gp & 31;
    #pragma unroll
    for (int i = 0; i < 8; ++i) {
        const int zz = zi + i * 8;
        const unsigned int lo = tile[gp][zz], hi = tile[gp + 1][zz];
        *(unsigned int*)(zt + ((size_t)(b * 128 + c) * 128 + z0 + zz) * 32 + gi)
            = lo | (hi << 16);
    }
}

// Block = (b, 32 t) x 128 z x 4096 g.  8 waves = kh(4-way g-split) x mt(2).
// mt-partner waves read identical B-frags -> L1 hit for the second reader,
// halving L2->L1 traffic vs M=16.  A in-register, no main-loop barriers.
__global__ __launch_bounds__(512, 4)
void setconv_main(const float* __restrict__ xt,
                  const float* __restrict__ xg,
                  const float* __restrict__ lsp,
                  const unsigned short* __restrict__ Zt,
                  float* __restrict__ out)
{
    __shared__ float red[16384];              // 64 KB: 4 slots x 16 planes x 256 f

    // XCD swizzle: 256 blocks; bx = tt2*8 + b*2 + p -> same-b blocks on 2 XCDs
    const int bx = blockIdx.x;
    const int b  = (bx >> 1) & 3;
    const int tt = ((bx >> 3) << 1) | (bx & 1);   // 0..63
    const int tid  = threadIdx.x;
    const int w    = tid >> 6;
    const int lane = tid & 63;
    const int quad = lane >> 4;
    const int l15  = lane & 15;
    const int kh   = w >> 1;                  // 0..3, g-range owner
    const int mt   = w & 1;                   // t-half within block
    const int t0   = tt * 32;

    float c00, c01, c10, c11;
    {
        const float h = -0.72134752f;         // -0.5*log2(e)
        float ls;
        ls = 1e-5f + softplus_f(lsp[0]); c00 = h / (ls * ls);
        ls = 1e-5f + softplus_f(lsp[1]); c01 = h / (ls * ls);
        ls = 1e-5f + softplus_f(lsp[2]); c10 = h / (ls * ls);
        ls = 1e-5f + softplus_f(lsp[3]); c11 = h / (ls * ls);
    }

    // A-frag row m = l15 -> per-lane t constants (t-row = t0 + mt*16 + l15)
    const float xt0 = xt[(size_t)(b * NT_ + t0 + mt * 16 + l15) * 2 + 0];
    const float xt1 = xt[(size_t)(b * NT_ + t0 + mt * 16 + l15) * 2 + 1];

    f32x4 acc[2][8];
    #pragma unroll
    for (int k = 0; k < 2; ++k)
        #pragma unroll
        for (int n = 0; n < 8; ++n) acc[k][n] = (f32x4)0.0f;

    const int g0 = kh * 1024;                 // this kh's g-range (32 chunks)
    // tiled B base: chunk c = kh*32 + ch, z-row = nt*16 + l15, gi = quad*8
    const unsigned short* zb = Zt + ((size_t)(b * 128 + kh * 32) * 128 + l15) * 32
                               + quad * 8;
    const float* xgp = xg + (size_t)(b * G_ + g0 + quad * 8) * 2;

    #pragma unroll 2
    for (int ch = 0; ch < 32; ++ch) {
        // B-frags nt 0..3 (contiguous 1 KB per instr; mt-partner hits L1)
        bf16x8 bzA[4];
        #pragma unroll
        for (int nt = 0; nt < 4; ++nt)
            bzA[nt] = *(const bf16x8*)(zb + (size_t)ch * 4096 + nt * 512);
        // xg for this quad's 8 g-slots
        const float* xp = xgp + ch * 64;
        const float4 xv0 = *(const float4*)(xp + 0);
        const float4 xv1 = *(const float4*)(xp + 4);
        const float4 xv2 = *(const float4*)(xp + 8);
        const float4 xv3 = *(const float4*)(xp + 12);
        float gx[8], gy[8];
        gx[0]=xv0.x; gy[0]=xv0.y; gx[1]=xv0.z; gy[1]=xv0.w;
        gx[2]=xv1.x; gy[2]=xv1.y; gx[3]=xv1.z; gy[3]=xv1.w;
        gx[4]=xv2.x; gy[4]=xv2.y; gx[5]=xv2.z; gy[5]=xv2.w;
        gx[6]=xv3.x; gy[6]=xv3.y; gx[7]=xv3.z; gy[7]=xv3.w;
        unsigned int w0b[8], w1b[8];
        #pragma unroll
        for (int j = 0; j < 8; ++j) {
            const float d0 = xt0 - gx[j];
            const float d1 = xt1 - gy[j];
            const float q0 = d0 * d0;
            const float q1 = d1 * d1;
            const float e0 = fmaf(q1, c10, q0 * c00);
            const float e1 = fmaf(q1, c11, q0 * c01);
            w0b[j] = __float_as_uint(__builtin_amdgcn_exp2f(e0));
            w1b[j] = __float_as_uint(__builtin_amdgcn_exp2f(e1));
        }
        union { bf16x8 v; unsigned int u[4]; } a0, a1;
        #pragma unroll
        for (int h = 0; h < 4; ++h) {
            a0.u[h] = __builtin_amdgcn_perm(w0b[2*h+1], w0b[2*h], 0x07060302u);
            a1.u[h] = __builtin_amdgcn_perm(w1b[2*h+1], w1b[2*h], 0x07060302u);
        }
        // B-frags nt 4..7
        bf16x8 bzB[4];
        #pragma unroll
        for (int nt = 0; nt < 4; ++nt)
            bzB[nt] = *(const bf16x8*)(zb + (size_t)ch * 4096 + (nt + 4) * 512);
        #pragma unroll
        for (int nt = 0; nt < 4; ++nt) {
            acc[0][nt] = __builtin_amdgcn_mfma_f32_16x16x32_bf16(a0.v, bzA[nt], acc[0][nt], 0, 0, 0);
            acc[1][nt] = __builtin_amdgcn_mfma_f32_16x16x32_bf16(a1.v, bzA[nt], acc[1][nt], 0, 0, 0);
        }
        #pragma unroll
        for (int nt = 0; nt < 4; ++nt) {
            acc[0][nt+4] = __builtin_amdgcn_mfma_f32_16x16x32_bf16(a0.v, bzB[nt], acc[0][nt+4], 0, 0, 0);
            acc[1][nt+4] = __builtin_amdgcn_mfma_f32_16x16x32_bf16(a1.v, bzB[nt], acc[1][nt+4], 0, 0, 0);
        }
    }

    // ---- 2-round kh-reduction (per mt), then kh==0 stores ----
    #define RED_W(slot) { \
        float* bp = &red[(slot) * 4096 + lane * 4]; \
        _Pragma("unroll") \
        for (int k = 0; k < 2; ++k) \
            _Pragma("unroll") \
            for (int n = 0; n < 8; ++n) \
                *(f32x4*)(bp + (k * 8 + n) * 256) = acc[k][n]; }
    #define RED_A(slot) { \
        const float* bp = &red[(slot) * 4096 + lane * 4]; \
        _Pragma("unroll") \
        for (int k = 0; k < 2; ++k) \
            _Pragma("unroll") \
            for (int n = 0; n < 8; ++n) \
                acc[k][n] += *(const f32x4*)(bp + (k * 8 + n) * 256); }

    if (kh >= 2) RED_W(mt * 2 + kh - 2);
    __syncthreads();
    if (kh < 2)  RED_A(mt * 2 + kh);
    if (kh == 1) RED_W(mt * 2 + 1);
    __syncthreads();
    if (kh == 0) {
        RED_A(mt * 2 + 1);
        const int tr = t0 + mt * 16 + quad * 4;
        #pragma unroll
        for (int nt = 0; nt < 8; ++nt) {
            float* ob = out + (size_t)(b * NT_ + tr) * (DZ_ * 2) + (nt * 16 + l15) * 2;
            #pragma unroll
            for (int r = 0; r < 4; ++r)
                *(float2*)(ob + (size_t)r * (DZ_ * 2)) =
                    make_float2(acc[0][nt][r], acc[1][nt][r]);
        }
    }
    #undef RED_W
    #undef RED_A
}

extern "C" void kernel_launch(void* const* d_in, const int* in_sizes, int n_in,
                              void* d_out, int out_size, void* d_ws, size_t ws_size,
                              hipStream_t stream)
{
    const float* x_grid = (const float*)d_in[0];   // (4,64,64,2)
    const float* z_grid = (const float*)d_in[1];   // (4,64,64,128)
    const float* xt     = (const float*)d_in[2];   // (4,2048,2)
    const float* lsp    = (const float*)d_in[3];   // (2,2)
    float* out = (float*)d_out;                    // (4,2048,256) fp32
    unsigned short* Zt = (unsigned short*)d_ws;    // tiled, 4 MB

    hipLaunchKernelGGL(transpose_z, dim3(512), dim3(256), 0, stream, z_grid, Zt);
    hipLaunchKernelGGL(setconv_main, dim3(256), dim3(512), 0, stream,
                       xt, x_grid, lsp, Zt, out);
}

// Round 8
// 113.884 us; speedup vs baseline: 1.1788x; 1.1788x over previous
//
#include <hip/hip_runtime.h>
#include <hip/hip_bf16.h>
#include <cmath>

#define B_   4
#define NT_  2048
#define G_   4096
#define DZ_  128

typedef __attribute__((ext_vector_type(8))) short bf16x8;
typedef __attribute__((ext_vector_type(4))) float f32x4;

__device__ __forceinline__ float softplus_f(float x) {
    return fmaxf(x, 0.0f) + log1pf(expf(-fabsf(x)));
}

// z_grid (B,G,DZ) fp32 -> Zt2 tiled bf16: Zt2[((b*128 + c)*128 + z)*32 + gi],
// c = g>>5, gi = g&31.  B-fragments become contiguous 1 KB bursts.
__global__ __launch_bounds__(256, 1)
void transpose_z(const float* __restrict__ z, unsigned short* __restrict__ zt)
{
    __shared__ unsigned short tile[64][66];
    const int bx = blockIdx.x;                // 4b * 64gt * 2zt = 512
    const int zti = bx & 1;
    const int gt  = (bx >> 1) & 63;
    const int b   = bx >> 7;
    const int g0 = gt * 64, z0 = zti * 64;
    const int tid = threadIdx.x;
    const int zl = tid & 63, gl = tid >> 6;
    #pragma unroll
    for (int i = 0; i < 16; ++i) {
        const int g = gl + i * 4;
        const float v = z[(size_t)(b * G_ + g0 + g) * DZ_ + z0 + zl];
        unsigned int u = __float_as_uint(v);
        u = u + 0x7FFFu + ((u >> 16) & 1u);   // RNE to bf16
        tile[g][zl] = (unsigned short)(u >> 16);
    }
    __syncthreads();
    const int gp = (tid & 31) * 2, zi = tid >> 5;
    const int c  = (g0 + gp) >> 5, gi = gp & 31;
    #pragma unroll
    for (int i = 0; i < 8; ++i) {
        const int zz = zi + i * 8;
        const unsigned int lo = tile[gp][zz], hi = tile[gp + 1][zz];
        *(unsigned int*)(zt + ((size_t)(b * 128 + c) * 128 + z0 + zz) * 32 + gi)
            = lo | (hi << 16);
    }
}

// Block = (b, 16 t) x 128 z x 4096 g.  8 waves = 8-way kh g-split (512 g each).
// A (weights) in-register from an LDS per-g table (xg off the TCP path);
// B (Zt2, tiled) direct from L2.  Epilogue: 3-round LDS k-reduction (aliases
// the table region -- barrier before first reduction write).
__global__ __launch_bounds__(512, 4)
void setconv_main(const float* __restrict__ xt,
                  const float* __restrict__ xg,
                  const float* __restrict__ lsp,
                  const unsigned short* __restrict__ Zt,
                  float* __restrict__ out)
{
    __shared__ float lds[16384];              // 64 KB: tabA|tabU, aliased by red

    // XCD swizzle: bx = tt2*8 + b*2 + p -> same-b blocks on 2 XCDs
    const int bx = blockIdx.x;
    const int b  = (bx >> 1) & 3;
    const int tt = ((bx >> 3) << 1) | (bx & 1);   // 0..127
    const int tid  = threadIdx.x;
    const int w    = tid >> 6;                // = kh, 0..7
    const int lane = tid & 63;
    const int quad = lane >> 4;
    const int l15  = lane & 15;
    const int t0   = tt * 16;

    float c00, c01, c10, c11;
    {
        const float h = -0.72134752f;         // -0.5*log2(e)
        float ls;
        ls = 1e-5f + softplus_f(lsp[0]); c00 = h / (ls * ls);
        ls = 1e-5f + softplus_f(lsp[1]); c01 = h / (ls * ls);
        ls = 1e-5f + softplus_f(lsp[2]); c10 = h / (ls * ls);
        ls = 1e-5f + softplus_f(lsp[3]); c11 = h / (ls * ls);
    }

    // ---- build per-g table in LDS: tabA=(gx,gy), tabU=(U0,U1) ----
    float2* const tabA = (float2*)lds;        // [4096]
    float2* const tabU = (float2*)(lds + 8192); // [4096]
    {
        const float2* xgb2 = (const float2*)(xg + (size_t)b * G_ * 2);
        #pragma unroll
        for (int i = 0; i < 8; ++i) {
            const int g = tid + i * 512;
            const float2 p = xgb2[g];
            tabA[g] = p;
            tabU[g] = make_float2(fmaf(c10, p.y * p.y, c00 * p.x * p.x),
                                  fmaf(c11, p.y * p.y, c01 * p.x * p.x));
        }
    }

    // per-lane t constants (A-frag row m = l15)
    const float xt0 = xt[(size_t)(b * NT_ + t0 + l15) * 2 + 0];
    const float xt1 = xt[(size_t)(b * NT_ + t0 + l15) * 2 + 1];
    const float At0 = fmaf(c10, xt1 * xt1, c00 * xt0 * xt0);
    const float At1 = fmaf(c11, xt1 * xt1, c01 * xt0 * xt0);
    const float nP00 = -2.0f * c00 * xt0, nP10 = -2.0f * c10 * xt1;
    const float nP01 = -2.0f * c01 * xt0, nP11 = -2.0f * c11 * xt1;

    f32x4 acc[2][8];
    #pragma unroll
    for (int k = 0; k < 2; ++k)
        #pragma unroll
        for (int n = 0; n < 8; ++n) acc[k][n] = (f32x4)0.0f;

    // tiled B base: chunk c = w*16 + ch, z-row = nt*16 + l15, gi = quad*8
    const unsigned short* zb = Zt + ((size_t)(b * 128 + w * 16) * 128 + l15) * 32
                               + quad * 8;
    const int gq = w * 512 + quad * 8;        // this wave's g base for weights

    __syncthreads();                          // table ready

    #pragma unroll 2
    for (int ch = 0; ch < 16; ++ch) {
        // B-frags nt 0..3 (contiguous 1 KB per instr)
        bf16x8 bzA[4];
        #pragma unroll
        for (int nt = 0; nt < 4; ++nt)
            bzA[nt] = *(const bf16x8*)(zb + (size_t)ch * 4096 + nt * 512);
        const int g = gq + ch * 32;
        unsigned int w0b[8], w1b[8];
        #pragma unroll
        for (int j = 0; j < 8; ++j) {
            const float2 gxy = tabA[g + j];
            const float2 uv  = tabU[g + j];
            const float e0 = fmaf(gxy.y, nP10, fmaf(gxy.x, nP00, At0 + uv.x));
            const float e1 = fmaf(gxy.y, nP11, fmaf(gxy.x, nP01, At1 + uv.y));
            w0b[j] = __float_as_uint(__builtin_amdgcn_exp2f(e0));
            w1b[j] = __float_as_uint(__builtin_amdgcn_exp2f(e1));
        }
        union { bf16x8 v; unsigned int u[4]; } a0, a1;
        #pragma unroll
        for (int h = 0; h < 4; ++h) {
            a0.u[h] = __builtin_amdgcn_perm(w0b[2*h+1], w0b[2*h], 0x07060302u);
            a1.u[h] = __builtin_amdgcn_perm(w1b[2*h+1], w1b[2*h], 0x07060302u);
        }
        // B-frags nt 4..7
        bf16x8 bzB[4];
        #pragma unroll
        for (int nt = 0; nt < 4; ++nt)
            bzB[nt] = *(const bf16x8*)(zb + (size_t)ch * 4096 + (nt + 4) * 512);
        #pragma unroll
        for (int nt = 0; nt < 4; ++nt) {
            acc[0][nt] = __builtin_amdgcn_mfma_f32_16x16x32_bf16(a0.v, bzA[nt], acc[0][nt], 0, 0, 0);
            acc[1][nt] = __builtin_amdgcn_mfma_f32_16x16x32_bf16(a1.v, bzA[nt], acc[1][nt], 0, 0, 0);
        }
        #pragma unroll
        for (int nt = 0; nt < 4; ++nt) {
            acc[0][nt+4] = __builtin_amdgcn_mfma_f32_16x16x32_bf16(a0.v, bzB[nt], acc[0][nt+4], 0, 0, 0);
            acc[1][nt+4] = __builtin_amdgcn_mfma_f32_16x16x32_bf16(a1.v, bzB[nt], acc[1][nt+4], 0, 0, 0);
        }
    }

    // ---- 3-round k-reduction over the 8 kh-waves (aliases the table LDS) ----
    float* const red = lds;
    #define RED_W(slot) { \
        float* bp = &red[(slot) * 4096 + lane * 4]; \
        _Pragma("unroll") \
        for (int k = 0; k < 2; ++k) \
            _Pragma("unroll") \
            for (int n = 0; n < 8; ++n) \
                *(f32x4*)(bp + (k * 8 + n) * 256) = acc[k][n]; }
    #define RED_A(slot) { \
        const float* bp = &red[(slot) * 4096 + lane * 4]; \
        _Pragma("unroll") \
        for (int k = 0; k < 2; ++k) \
            _Pragma("unroll") \
            for (int n = 0; n < 8; ++n) \
                acc[k][n] += *(const f32x4*)(bp + (k * 8 + n) * 256); }

    __syncthreads();                          // all table reads done before alias
    if (w >= 4) RED_W(w - 4);
    __syncthreads();
    if (w < 4) RED_A(w);
    if (w == 2 || w == 3) RED_W(w);
    __syncthreads();
    if (w < 2) RED_A(w + 2);
    if (w == 1) RED_W(3);
    __syncthreads();
    if (w == 0) {
        RED_A(3);
        const int tr = t0 + quad * 4;
        #pragma unroll
        for (int nt = 0; nt < 8; ++nt) {
            float* ob = out + (size_t)(b * NT_ + tr) * (DZ_ * 2) + (nt * 16 + l15) * 2;
            #pragma unroll
            for (int r = 0; r < 4; ++r)
                *(float2*)(ob + (size_t)r * (DZ_ * 2)) =
                    make_float2(acc[0][nt][r], acc[1][nt][r]);
        }
    }
    #undef RED_W
    #undef RED_A
}

extern "C" void kernel_launch(void* const* d_in, const int* in_sizes, int n_in,
                              void* d_out, int out_size, void* d_ws, size_t ws_size,
                              hipStream_t stream)
{
    const float* x_grid = (const float*)d_in[0];   // (4,64,64,2)
    const float* z_grid = (const float*)d_in[1];   // (4,64,64,128)
    const float* xt     = (const float*)d_in[2];   // (4,2048,2)
    const float* lsp    = (const float*)d_in[3];   // (2,2)
    float* out = (float*)d_out;                    // (4,2048,256) fp32
    unsigned short* Zt = (unsigned short*)d_ws;    // tiled, 4 MB

    hipLaunchKernelGGL(transpose_z, dim3(512), dim3(256), 0, stream, z_grid, Zt);
    hipLaunchKernelGGL(setconv_main, dim3(512), dim3(512), 0, stream,
                       xt, x_grid, lsp, Zt, out);
}

// Round 9
// 110.693 us; speedup vs baseline: 1.2128x; 1.0288x over previous
//
#include <hip/hip_runtime.h>
#include <hip/hip_bf16.h>
#include <cmath>

#define B_   4
#define NT_  2048
#define G_   4096
#define DZ_  128

typedef __attribute__((ext_vector_type(8))) short bf16x8;
typedef __attribute__((ext_vector_type(4))) float f32x4;

__device__ __forceinline__ float softplus_f(float x) {
    return fmaxf(x, 0.0f) + log1pf(expf(-fabsf(x)));
}

// z_grid (B,G,DZ) fp32 -> Zt2 tiled bf16: Zt2[((b*128 + c)*128 + z)*32 + gi],
// c = g>>5, gi = g&31.  B-fragments become contiguous 1 KB bursts.
__global__ __launch_bounds__(256, 1)
void transpose_z(const float* __restrict__ z, unsigned short* __restrict__ zt)
{
    __shared__ unsigned short tile[64][66];
    const int bx = blockIdx.x;                // 4b * 64gt * 2zt = 512
    const int zti = bx & 1;
    const int gt  = (bx >> 1) & 63;
    const int b   = bx >> 7;
    const int g0 = gt * 64, z0 = zti * 64;
    const int tid = threadIdx.x;
    const int zl = tid & 63, gl = tid >> 6;
    #pragma unroll
    for (int i = 0; i < 16; ++i) {
        const int g = gl + i * 4;
        const float v = z[(size_t)(b * G_ + g0 + g) * DZ_ + z0 + zl];
        unsigned int u = __float_as_uint(v);
        u = u + 0x7FFFu + ((u >> 16) & 1u);   // RNE to bf16
        tile[g][zl] = (unsigned short)(u >> 16);
    }
    __syncthreads();
    const int gp = (tid & 31) * 2, zi = tid >> 5;
    const int c  = (g0 + gp) >> 5, gi = gp & 31;
    #pragma unroll
    for (int i = 0; i < 8; ++i) {
        const int zz = zi + i * 8;
        const unsigned int lo = tile[gp][zz], hi = tile[gp + 1][zz];
        *(unsigned int*)(zt + ((size_t)(b * 128 + c) * 128 + z0 + zz) * 32 + gi)
            = lo | (hi << 16);
    }
}

// Block = (b, 16 t) x 128 z x 4096 g.  8 waves = 8-way kh g-split (512 g each).
// A (weights) in-register; B (Zt2, tiled) direct from L2; no main-loop
// LDS/barriers.  Fully-unrolled, wave-rotated K-loop so the scheduler can
// software-pipeline loads across chunks.  Epilogue: 3-round LDS k-reduction.
__global__ __launch_bounds__(512, 4)
void setconv_main(const float* __restrict__ xt,
                  const float* __restrict__ xg,
                  const float* __restrict__ lsp,
                  const unsigned short* __restrict__ Zt,
                  float* __restrict__ out)
{
    __shared__ float red[16384];              // 64 KB: 4 slots x 16 planes x 256 f

    // XCD swizzle: bx = tt2*8 + b*2 + p -> same-b blocks on 2 XCDs
    const int bx = blockIdx.x;
    const int b  = (bx >> 1) & 3;
    const int tt = ((bx >> 3) << 1) | (bx & 1);   // 0..127
    const int tid  = threadIdx.x;
    const int w    = tid >> 6;                // = kh, 0..7
    const int lane = tid & 63;
    const int quad = lane >> 4;
    const int l15  = lane & 15;
    const int t0   = tt * 16;

    float c00, c01, c10, c11;
    {
        const float h = -0.72134752f;         // -0.5*log2(e)
        float ls;
        ls = 1e-5f + softplus_f(lsp[0]); c00 = h / (ls * ls);
        ls = 1e-5f + softplus_f(lsp[1]); c01 = h / (ls * ls);
        ls = 1e-5f + softplus_f(lsp[2]); c10 = h / (ls * ls);
        ls = 1e-5f + softplus_f(lsp[3]); c11 = h / (ls * ls);
    }

    // A-frag row m = l15 -> per-lane t constants
    const float xt0 = xt[(size_t)(b * NT_ + t0 + l15) * 2 + 0];
    const float xt1 = xt[(size_t)(b * NT_ + t0 + l15) * 2 + 1];

    f32x4 acc[2][8];
    #pragma unroll
    for (int k = 0; k < 2; ++k)
        #pragma unroll
        for (int n = 0; n < 8; ++n) acc[k][n] = (f32x4)0.0f;

    const int g0 = w * 512;                   // this wave's k-range
    // tiled B base: chunk c = w*16 + ch, z-row = nt*16 + l15, gi = quad*8
    const unsigned short* zb = Zt + ((size_t)(b * 128 + w * 16) * 128 + l15) * 32
                               + quad * 8;
    const float* xgp = xg + (size_t)(b * G_ + g0 + quad * 8) * 2;

    #pragma unroll
    for (int i = 0; i < 16; ++i) {
        const int ch = (i + 2 * w) & 15;      // per-wave rotation (L2 spread)
        // B-frags nt 0..3 (contiguous 1 KB per instr)
        bf16x8 bzA[4];
        #pragma unroll
        for (int nt = 0; nt < 4; ++nt)
            bzA[nt] = *(const bf16x8*)(zb + (size_t)ch * 4096 + nt * 512);
        // xg for this quad's 8 g-slots
        const float* xp = xgp + ch * 64;
        const float4 xv0 = *(const float4*)(xp + 0);
        const float4 xv1 = *(const float4*)(xp + 4);
        const float4 xv2 = *(const float4*)(xp + 8);
        const float4 xv3 = *(const float4*)(xp + 12);
        float gx[8], gy[8];
        gx[0]=xv0.x; gy[0]=xv0.y; gx[1]=xv0.z; gy[1]=xv0.w;
        gx[2]=xv1.x; gy[2]=xv1.y; gx[3]=xv1.z; gy[3]=xv1.w;
        gx[4]=xv2.x; gy[4]=xv2.y; gx[5]=xv2.z; gy[5]=xv2.w;
        gx[6]=xv3.x; gy[6]=xv3.y; gx[7]=xv3.z; gy[7]=xv3.w;
        unsigned int w0b[8], w1b[8];
        #pragma unroll
        for (int j = 0; j < 8; ++j) {
            const float d0 = xt0 - gx[j];
            const float d1 = xt1 - gy[j];
            const float q0 = d0 * d0;
            const float q1 = d1 * d1;
            const float e0 = fmaf(q1, c10, q0 * c00);
            const float e1 = fmaf(q1, c11, q0 * c01);
            w0b[j] = __float_as_uint(__builtin_amdgcn_exp2f(e0));
            w1b[j] = __float_as_uint(__builtin_amdgcn_exp2f(e1));
        }
        union { bf16x8 v; unsigned int u[4]; } a0, a1;
        #pragma unroll
        for (int h = 0; h < 4; ++h) {
            a0.u[h] = __builtin_amdgcn_perm(w0b[2*h+1], w0b[2*h], 0x07060302u);
            a1.u[h] = __builtin_amdgcn_perm(w1b[2*h+1], w1b[2*h], 0x07060302u);
        }
        // B-frags nt 4..7
        bf16x8 bzB[4];
        #pragma unroll
        for (int nt = 0; nt < 4; ++nt)
            bzB[nt] = *(const bf16x8*)(zb + (size_t)ch * 4096 + (nt + 4) * 512);
        #pragma unroll
        for (int nt = 0; nt < 4; ++nt) {
            acc[0][nt] = __builtin_amdgcn_mfma_f32_16x16x32_bf16(a0.v, bzA[nt], acc[0][nt], 0, 0, 0);
            acc[1][nt] = __builtin_amdgcn_mfma_f32_16x16x32_bf16(a1.v, bzA[nt], acc[1][nt], 0, 0, 0);
        }
        #pragma unroll
        for (int nt = 0; nt < 4; ++nt) {
            acc[0][nt+4] = __builtin_amdgcn_mfma_f32_16x16x32_bf16(a0.v, bzB[nt], acc[0][nt+4], 0, 0, 0);
            acc[1][nt+4] = __builtin_amdgcn_mfma_f32_16x16x32_bf16(a1.v, bzB[nt], acc[1][nt+4], 0, 0, 0);
        }
    }

    // ---- 3-round k-reduction over the 8 kh-waves ----
    #define RED_W(slot) { \
        float* bp = &red[(slot) * 4096 + lane * 4]; \
        _Pragma("unroll") \
        for (int k = 0; k < 2; ++k) \
            _Pragma("unroll") \
            for (int n = 0; n < 8; ++n) \
                *(f32x4*)(bp + (k * 8 + n) * 256) = acc[k][n]; }
    #define RED_A(slot) { \
        const float* bp = &red[(slot) * 4096 + lane * 4]; \
        _Pragma("unroll") \
        for (int k = 0; k < 2; ++k) \
            _Pragma("unroll") \
            for (int n = 0; n < 8; ++n) \
                acc[k][n] += *(const f32x4*)(bp + (k * 8 + n) * 256); }

    __syncthreads();
    if (w >= 4) RED_W(w - 4);
    __syncthreads();
    if (w < 4) RED_A(w);
    if (w == 2 || w == 3) RED_W(w);
    __syncthreads();
    if (w < 2) RED_A(w + 2);
    if (w == 1) RED_W(3);
    __syncthreads();
    if (w == 0) {
        RED_A(3);
        const int tr = t0 + quad * 4;
        #pragma unroll
        for (int nt = 0; nt < 8; ++nt) {
            float* ob = out + (size_t)(b * NT_ + tr) * (DZ_ * 2) + (nt * 16 + l15) * 2;
            #pragma unroll
            for (int r = 0; r < 4; ++r)
                *(float2*)(ob + (size_t)r * (DZ_ * 2)) =
                    make_float2(acc[0][nt][r], acc[1][nt][r]);
        }
    }
    #undef RED_W
    #undef RED_A
}

extern "C" void kernel_launch(void* const* d_in, const int* in_sizes, int n_in,
                              void* d_out, int out_size, void* d_ws, size_t ws_size,
                              hipStream_t stream)
{
    const float* x_grid = (const float*)d_in[0];   // (4,64,64,2)
    const float* z_grid = (const float*)d_in[1];   // (4,64,64,128)
    const float* xt     = (const float*)d_in[2];   // (4,2048,2)
    const float* lsp    = (const float*)d_in[3];   // (2,2)
    float* out = (float*)d_out;                    // (4,2048,256) fp32
    unsigned short* Zt = (unsigned short*)d_ws;    // tiled, 4 MB

    hipLaunchKernelGGL(transpose_z, dim3(512), dim3(256), 0, stream, z_grid, Zt);
    hipLaunchKernelGGL(setconv_main, dim3(512), dim3(512), 0, stream,
                       xt, x_grid, lsp, Zt, out);
}

// Round 10
// 103.347 us; speedup vs baseline: 1.2990x; 1.0711x over previous
//
#include <hip/hip_runtime.h>
#include <hip/hip_bf16.h>
#include <cmath>

#define B_   4
#define NT_  2048
#define G_   4096
#define DZ_  128

typedef __attribute__((ext_vector_type(8))) short bf16x8;
typedef __attribute__((ext_vector_type(4))) float f32x4;

__device__ __forceinline__ float softplus_f(float x) {
    return fmaxf(x, 0.0f) + log1pf(expf(-fabsf(x)));
}

// async 16B global -> LDS (lane i lands at ldst + 16*i; ldst wave-uniform)
__device__ __forceinline__ void gl2lds16(const void* gsrc, void* ldst) {
    __builtin_amdgcn_global_load_lds(
        (const __attribute__((address_space(1))) unsigned int*)gsrc,
        (__attribute__((address_space(3))) unsigned int*)ldst, 16, 0, 0);
}

// z_grid (B,G,DZ) fp32 -> Zt2 tiled bf16: Zt2[((b*128 + c)*128 + z)*32 + gi],
// c = g>>5, gi = g&31.  Each 8 KB chunk-tile is contiguous.
__global__ __launch_bounds__(256, 1)
void transpose_z(const float* __restrict__ z, unsigned short* __restrict__ zt)
{
    __shared__ unsigned short tile[64][66];
    const int bx = blockIdx.x;                // 4b * 64gt * 2zt = 512
    const int zti = bx & 1;
    const int gt  = (bx >> 1) & 63;
    const int b   = bx >> 7;
    const int g0 = gt * 64, z0 = zti * 64;
    const int tid = threadIdx.x;
    const int zl = tid & 63, gl = tid >> 6;
    #pragma unroll
    for (int i = 0; i < 16; ++i) {
        const int g = gl + i * 4;
        const float v = z[(size_t)(b * G_ + g0 + g) * DZ_ + z0 + zl];
        unsigned int u = __float_as_uint(v);
        u = u + 0x7FFFu + ((u >> 16) & 1u);   // RNE to bf16
        tile[g][zl] = (unsigned short)(u >> 16);
    }
    __syncthreads();
    const int gp = (tid & 31) * 2, zi = tid >> 5;
    const int c  = (g0 + gp) >> 5, gi = gp & 31;
    #pragma unroll
    for (int i = 0; i < 8; ++i) {
        const int zz = zi + i * 8;
        const unsigned int lo = tile[gp][zz], hi = tile[gp + 1][zz];
        *(unsigned int*)(zt + ((size_t)(b * 128 + c) * 128 + z0 + zz) * 32 + gi)
            = lo | (hi << 16);
    }
}

// Block = (b, 16 t) x 128 z x 4096 g.  8 waves = 8-way kh g-split (512 g each).
// Pipelined: B DMAed into a PRIVATE per-wave LDS slot (no barriers), consumed
// via ds_read_b128; xg register-prefetched one chunk ahead; weights in-register.
__global__ __launch_bounds__(512, 4)
void setconv_main(const float* __restrict__ xt,
                  const float* __restrict__ xg,
                  const float* __restrict__ lsp,
                  const unsigned short* __restrict__ Zt,
                  float* __restrict__ out)
{
    __shared__ __align__(16) unsigned short lds[32768];  // 64 KB: 8 wave-tiles / red

    // XCD swizzle: bx = tt2*8 + b*2 + p -> same-b blocks on 2 XCDs
    const int bx = blockIdx.x;
    const int b  = (bx >> 1) & 3;
    const int tt = ((bx >> 3) << 1) | (bx & 1);   // 0..127
    const int tid  = threadIdx.x;
    const int w    = tid >> 6;                // = kh, 0..7
    const int lane = tid & 63;
    const int quad = lane >> 4;
    const int l15  = lane & 15;
    const int t0   = tt * 16;

    float c00, c01, c10, c11;
    {
        const float h = -0.72134752f;         // -0.5*log2(e)
        float ls;
        ls = 1e-5f + softplus_f(lsp[0]); c00 = h / (ls * ls);
        ls = 1e-5f + softplus_f(lsp[1]); c01 = h / (ls * ls);
        ls = 1e-5f + softplus_f(lsp[2]); c10 = h / (ls * ls);
        ls = 1e-5f + softplus_f(lsp[3]); c11 = h / (ls * ls);
    }

    // A-frag row m = l15 -> per-lane t constants
    const float xt0 = xt[(size_t)(b * NT_ + t0 + l15) * 2 + 0];
    const float xt1 = xt[(size_t)(b * NT_ + t0 + l15) * 2 + 1];

    f32x4 acc[2][8];
    #pragma unroll
    for (int k = 0; k < 2; ++k)
        #pragma unroll
        for (int n = 0; n < 8; ++n) acc[k][n] = (f32x4)0.0f;

    unsigned short* const mytile = lds + w * 4096;       // private 8 KB slot
    const float* xgq = xg + (size_t)(b * G_ + w * 512 + quad * 8) * 2;

    // prologue: xv(0) first (so weights(0) wait leaves stage(0) in flight)
    float4 xv0 = *(const float4*)(xgq + 0);
    float4 xv1 = *(const float4*)(xgq + 4);
    float4 xv2 = *(const float4*)(xgq + 8);
    float4 xv3 = *(const float4*)(xgq + 12);
    {
        const unsigned short* zs = Zt + (size_t)(b * 128 + w * 16) * 4096 + lane * 8;
        #pragma unroll
        for (int i = 0; i < 8; ++i)
            gl2lds16(zs + i * 512, mytile + i * 512);
    }

    #pragma unroll
    for (int ch = 0; ch < 16; ++ch) {
        // ---- weights(ch) from xv (loaded >=1 chunk ago; no fresh vm wait) ----
        float gx[8], gy[8];
        gx[0]=xv0.x; gy[0]=xv0.y; gx[1]=xv0.z; gy[1]=xv0.w;
        gx[2]=xv1.x; gy[2]=xv1.y; gx[3]=xv1.z; gy[3]=xv1.w;
        gx[4]=xv2.x; gy[4]=xv2.y; gx[5]=xv2.z; gy[5]=xv2.w;
        gx[6]=xv3.x; gy[6]=xv3.y; gx[7]=xv3.z; gy[7]=xv3.w;
        unsigned int w0b[8], w1b[8];
        #pragma unroll
        for (int j = 0; j < 8; ++j) {
            const float d0 = xt0 - gx[j];
            const float d1 = xt1 - gy[j];
            const float q0 = d0 * d0;
            const float q1 = d1 * d1;
            const float e0 = fmaf(q1, c10, q0 * c00);
            const float e1 = fmaf(q1, c11, q0 * c01);
            w0b[j] = __float_as_uint(__builtin_amdgcn_exp2f(e0));
            w1b[j] = __float_as_uint(__builtin_amdgcn_exp2f(e1));
        }
        union { bf16x8 v; unsigned int u[4]; } a0, a1;
        #pragma unroll
        for (int h = 0; h < 4; ++h) {
            a0.u[h] = __builtin_amdgcn_perm(w0b[2*h+1], w0b[2*h], 0x07060302u);
            a1.u[h] = __builtin_amdgcn_perm(w1b[2*h+1], w1b[2*h], 0x07060302u);
        }

        // ---- drain this chunk's DMA (issued a full phase ago), then xv(ch+1) ----
        __builtin_amdgcn_s_waitcnt(0x0F70);          // vmcnt(0)
        if (ch < 15) {
            const float* xp = xgq + (ch + 1) * 64;
            xv0 = *(const float4*)(xp + 0);
            xv1 = *(const float4*)(xp + 4);
            xv2 = *(const float4*)(xp + 8);
            xv3 = *(const float4*)(xp + 12);
        }

        // ---- consume LDS tile: ds_read_b128 + MFMA ----
        #pragma unroll
        for (int nt = 0; nt < 8; ++nt) {
            const bf16x8 bz = *(const bf16x8*)(mytile + nt * 512 + l15 * 32 + quad * 8);
            acc[0][nt] = __builtin_amdgcn_mfma_f32_16x16x32_bf16(a0.v, bz, acc[0][nt], 0, 0, 0);
            acc[1][nt] = __builtin_amdgcn_mfma_f32_16x16x32_bf16(a1.v, bz, acc[1][nt], 0, 0, 0);
        }

        // ---- stage(ch+1) into the (now fully-read) private tile ----
        if (ch < 15) {
            const unsigned short* zs = Zt + (size_t)(b * 128 + w * 16 + ch + 1) * 4096
                                       + lane * 8;
            #pragma unroll
            for (int i = 0; i < 8; ++i)
                gl2lds16(zs + i * 512, mytile + i * 512);
        }
    }

    // ---- 3-round k-reduction over the 8 kh-waves (aliases wave tiles) ----
    float* const red = (float*)lds;
    #define RED_W(slot) { \
        float* bp = &red[(slot) * 4096 + lane * 4]; \
        _Pragma("unroll") \
        for (int k = 0; k < 2; ++k) \
            _Pragma("unroll") \
            for (int n = 0; n < 8; ++n) \
                *(f32x4*)(bp + (k * 8 + n) * 256) = acc[k][n]; }
    #define RED_A(slot) { \
        const float* bp = &red[(slot) * 4096 + lane * 4]; \
        _Pragma("unroll") \
        for (int k = 0; k < 2; ++k) \
            _Pragma("unroll") \
            for (int n = 0; n < 8; ++n) \
                acc[k][n] += *(const f32x4*)(bp + (k * 8 + n) * 256); }

    __syncthreads();
    if (w >= 4) RED_W(w - 4);
    __syncthreads();
    if (w < 4) RED_A(w);
    if (w == 2 || w == 3) RED_W(w);
    __syncthreads();
    if (w < 2) RED_A(w + 2);
    if (w == 1) RED_W(3);
    __syncthreads();
    if (w == 0) {
        RED_A(3);
        const int tr = t0 + quad * 4;
        #pragma unroll
        for (int nt = 0; nt < 8; ++nt) {
            float* ob = out + (size_t)(b * NT_ + tr) * (DZ_ * 2) + (nt * 16 + l15) * 2;
            #pragma unroll
            for (int r = 0; r < 4; ++r)
                *(float2*)(ob + (size_t)r * (DZ_ * 2)) =
                    make_float2(acc[0][nt][r], acc[1][nt][r]);
        }
    }
    #undef RED_W
    #undef RED_A
}

extern "C" void kernel_launch(void* const* d_in, const int* in_sizes, int n_in,
                              void* d_out, int out_size, void* d_ws, size_t ws_size,
                              hipStream_t stream)
{
    const float* x_grid = (const float*)d_in[0];   // (4,64,64,2)
    const float* z_grid = (const float*)d_in[1];   // (4,64,64,128)
    const float* xt     = (const float*)d_in[2];   // (4,2048,2)
    const float* lsp    = (const float*)d_in[3];   // (2,2)
    float* out = (float*)d_out;                    // (4,2048,256) fp32
    unsigned short* Zt = (unsigned short*)d_ws;    // tiled, 4 MB

    hipLaunchKernelGGL(transpose_z, dim3(512), dim3(256), 0, stream, z_grid, Zt);
    hipLaunchKernelGGL(setconv_main, dim3(512), dim3(512), 0, stream,
                       xt, x_grid, lsp, Zt, out);
}